// Round 4
// baseline (213.249 us; speedup 1.0000x reference)
//
#include <hip/hip_runtime.h>
#include <hip/hip_bf16.h>

#define B_ 8192
#define I_ 512
#define H_ 1024
#define R_ 64

typedef __bf16 bf16x8 __attribute__((ext_vector_type(8)));
typedef short  s16x8  __attribute__((ext_vector_type(8)));
typedef float  f32x4  __attribute__((ext_vector_type(4)));

static __device__ __forceinline__ short f2bf(float f) {
    union { float f; unsigned u; } v; v.f = f;
    unsigned r = v.u + 0x7fffu + ((v.u >> 16) & 1u);
    return (short)(r >> 16);
}
// v_rcp_f32 (~1 ulp) instead of IEEE divide (no -ffast-math in harness).
static __device__ __forceinline__ float frcp_(float x) {
#if __has_builtin(__builtin_amdgcn_rcpf)
    return __builtin_amdgcn_rcpf(x);
#else
    float r; asm("v_rcp_f32 %0, %1" : "=v"(r) : "v"(x)); return r;
#endif
}
static __device__ __forceinline__ float sigmoidf_(float v) {
    return frcp_(1.f + __expf(-v));
}
static __device__ __forceinline__ float tanhf_(float v) {
    return 2.f * frcp_(1.f + __expf(-2.f * v)) - 1.f;
}

// ---------------------------------------------------------------------------
// Prep: uxT[64][512], uhT[64][1024], Vc[4096][128] (all bf16), coef_x[4][512],
// coef_h[4][1024] (f32). Coef section: one wave per j, lanes = rank r.
// 32768 + 65536 + 524288 + 98304 = 720896 = 2816 * 256 threads.
// ---------------------------------------------------------------------------
__global__ __launch_bounds__(256) void prep_kernel(
    const float* __restrict__ u_x, const float* __restrict__ u_h,
    const float* __restrict__ v_x, const float* __restrict__ v_h,
    short* __restrict__ uxT, short* __restrict__ uhT, short* __restrict__ Vc,
    float* __restrict__ coef_x, float* __restrict__ coef_h)
{
    int t = blockIdx.x * 256 + threadIdx.x;
    if (t < 64 * 512) {                       // uxT[r][k] = u_x[k][r], coalesced read
        int k = t >> 6, r = t & 63;
        uxT[r * 512 + k] = f2bf(u_x[t]);
        return;
    }
    t -= 64 * 512;
    if (t < 64 * 1024) {                      // uhT[r][k] = u_h[k][r]
        int k = t >> 6, r = t & 63;
        uhT[r * 1024 + k] = f2bf(u_h[t]);
        return;
    }
    t -= 64 * 1024;
    if (t < 4096 * 128) {                     // Vc = [v_x | v_h] rows, bf16
        int n = t >> 7, q = t & 127;
        Vc[t] = f2bf(q < 64 ? v_x[n * 64 + q] : v_h[n * 64 + (q - 64)]);
        return;
    }
    t -= 4096 * 128;
    if (t < 1536 * 64) {                      // coef: 1536 waves, one j each
        const int wid = t >> 6, lane = t & 63;
        const float* U; const float* V; float* C; int j, JN;
        if (wid < 512) { U = u_x; V = v_x; C = coef_x; j = wid;       JN = 512;  }
        else           { U = u_h; V = v_h; C = coef_h; j = wid - 512; JN = 1024; }
        const float uv = U[(size_t)j * 64 + lane];
        float s[4];
#pragma unroll
        for (int g = 0; g < 4; ++g)
            s[g] = uv * V[(size_t)(g * H_ + j) * 64 + lane];
#pragma unroll
        for (int off = 32; off >= 1; off >>= 1)
#pragma unroll
            for (int g = 0; g < 4; ++g)
                s[g] += __shfl_xor(s[g], off, 64);
        if (lane == 0)
#pragma unroll
            for (int g = 0; g < 4; ++g)
                C[g * JN + j] = s[g];
        return;
    }
}

// ---------------------------------------------------------------------------
// Stage 1: P[b][0:64] = x @ u_x, P[b][64:128] = h @ u_h  (bf16 MFMA).
// 256-thr blocks (4 waves), 16 batch rows per block -> grid (512, 2).
// ---------------------------------------------------------------------------
__global__ __launch_bounds__(256) void stage1_kernel(
    const float* __restrict__ x, const float* __restrict__ h,
    const short* __restrict__ uxT, const short* __restrict__ uhT,
    short* __restrict__ P)
{
    __shared__ short At[16 * 136];
    const int w = threadIdx.x >> 6, lane = threadIdx.x & 63;
    const int quad = lane >> 4, lr = lane & 15;
    const int n0 = w * 16;

    const float* X; const short* UT; int K, co;
    if (blockIdx.y == 0) { X = x; UT = uxT; K = I_; co = 0; }
    else                 { X = h; UT = uhT; K = H_; co = 64; }

    const int b0 = blockIdx.x * 16;
    const int srow = threadIdx.x >> 4;
    const int scol = (threadIdx.x & 15) * 8;

    f32x4 acc = {};
    const short* bp = UT + (size_t)(n0 + lr) * K + quad * 8;
    const short* arow = At + lr * 136 + quad * 8;
    const float* srcbase = X + (size_t)(b0 + srow) * K + scol;

    float4 c0 = ((const float4*)(srcbase))[0];
    float4 c1 = ((const float4*)(srcbase))[1];

    for (int k0 = 0; k0 < K; k0 += 128) {
        s16x8 p;
        p[0] = f2bf(c0.x); p[1] = f2bf(c0.y); p[2] = f2bf(c0.z); p[3] = f2bf(c0.w);
        p[4] = f2bf(c1.x); p[5] = f2bf(c1.y); p[6] = f2bf(c1.z); p[7] = f2bf(c1.w);
        __syncthreads();
        *(s16x8*)(At + srow * 136 + scol) = p;
        __syncthreads();
        if (k0 + 128 < K) {
            c0 = ((const float4*)(srcbase + k0 + 128))[0];
            c1 = ((const float4*)(srcbase + k0 + 128))[1];
        }
#pragma unroll
        for (int ks = 0; ks < 4; ++ks) {
            bf16x8 bfrag = *(const bf16x8*)(bp + k0 + ks * 32);
            bf16x8 afrag = *(const bf16x8*)(arow + ks * 32);
            acc = __builtin_amdgcn_mfma_f32_16x16x32_bf16(afrag, bfrag, acc, 0, 0, 0);
        }
    }

#pragma unroll
    for (int r = 0; r < 4; ++r)
        P[(size_t)(b0 + quad * 4 + r) * 128 + co + n0 + lr] = f2bf(acc[r]);
}

// ---------------------------------------------------------------------------
// Stage 2: gates = Vc @ P^T (note operand swap!) with fused LSTM epilogue.
// KEY CHANGE vs R2: swap the MFMA operand order -> D[j][b] instead of D[b][j].
// Since P and Vc are both row-major [item][k] and A/B fragments share the
// same lane mapping (idx=lane&15, k=(lane>>4)*8), the operand LOADS are
// byte-identical; only the intrinsic arg order changes. The C/D layout
// (col=lane&15=batch, row=quad*4+r=j) now gives each lane 4 CONSECUTIVE j
// at ONE batch row -> all epilogue traffic (x/h/c loads, h'/c' stores) is
// float4 (16 B/lane, 1024 B/instr) instead of scalar dword: 5 memory instrs
// per m-tile instead of 20. R0-R2 showed stage2 latency/issue-bound at
// 2 TB/s with all pipes idle; this quadruples bytes-in-flight per issued op.
// Output stores are non-temporal (streaming, never re-read) — note the
// ext-vector f32x4 type (clang vector), NOT HIP float4, for the builtin.
// Grid (B/64, H/64) = (128, 16), 256 thr = 4 independent waves.
// ---------------------------------------------------------------------------
__global__ __launch_bounds__(256) void stage2_kernel(
    const short* __restrict__ P, const short* __restrict__ Vc,
    const float* __restrict__ x, const float* __restrict__ h,
    const float* __restrict__ c,
    const float* __restrict__ coef_x, const float* __restrict__ coef_h,
    const float* __restrict__ b_x, const float* __restrict__ b_h,
    const float* __restrict__ dia_x, const float* __restrict__ dia_h,
    float* __restrict__ out)
{
    const int lane = threadIdx.x & 63;
    const int wv   = threadIdx.x >> 6;
    const int quad = lane >> 4, lr = lane & 15;
    const int b0 = blockIdx.x * 64;                 // rows shared by all 4 waves
    const int j0 = blockIdx.y * 64 + wv * 16;       // per-wave j-tile
    const int j4 = j0 + quad * 4;                   // this lane's 4 consecutive j
    const bool jx = (j0 < I_);                      // uniform per block (I_ % 64 == 0)

    // ---- prologue m-tile 0: issue the long-latency loads FIRST
    bf16x8 a[4];
#pragma unroll
    for (int ks = 0; ks < 4; ++ks)
        a[ks] = *(const bf16x8*)(P + (size_t)(b0 + lr) * 128 + ks * 32 + quad * 8);
    f32x4 xv = {}, hv, cv;
    {
        const int brow = b0 + lr;
        cv = *(const f32x4*)(c + (size_t)brow * H_ + j4);
        hv = *(const f32x4*)(h + (size_t)brow * H_ + j4);
        if (jx) xv = *(const f32x4*)(x + (size_t)brow * I_ + j4);
    }

    // ---- Vc operand (MFMA *A* operand now): 4 gates x 4 k-slices, VGPR-resident
    bf16x8 vfr[4][4];
#pragma unroll
    for (int g = 0; g < 4; ++g)
#pragma unroll
        for (int ks = 0; ks < 4; ++ks)
            vfr[g][ks] = *(const bf16x8*)(Vc + (size_t)(g * H_ + j0 + lr) * 128 + ks * 32 + quad * 8);

    // ---- per-lane j-quad constants (f32x4 loads, L2-hot, loop-invariant)
    float dx[4] = {}, dh[4], cx[4][4] = {}, ch[4][4], bs[4][4];
    {
        f32x4 t;
        if (jx) { t = *(const f32x4*)(dia_x + j4); dx[0]=t[0]; dx[1]=t[1]; dx[2]=t[2]; dx[3]=t[3]; }
        t = *(const f32x4*)(dia_h + j4); dh[0]=t[0]; dh[1]=t[1]; dh[2]=t[2]; dh[3]=t[3];
#pragma unroll
        for (int g = 0; g < 4; ++g) {
            if (jx) {
                t = *(const f32x4*)(coef_x + g * I_ + j4);
                cx[g][0]=t[0]; cx[g][1]=t[1]; cx[g][2]=t[2]; cx[g][3]=t[3];
            }
            t = *(const f32x4*)(coef_h + g * H_ + j4);
            ch[g][0]=t[0]; ch[g][1]=t[1]; ch[g][2]=t[2]; ch[g][3]=t[3];
            f32x4 tb = *(const f32x4*)(b_x + g * H_ + j4);
            f32x4 th = *(const f32x4*)(b_h + g * H_ + j4);
            bs[g][0]=tb[0]+th[0]; bs[g][1]=tb[1]+th[1]; bs[g][2]=tb[2]+th[2]; bs[g][3]=tb[3]+th[3];
        }
    }

    for (int mt = 0; mt < 4; ++mt) {
        // prefetch next m-tile's P-fragments + epilogue operands
        bf16x8 an[4];
        f32x4 xn = {}, hn, cn2;
        if (mt < 3) {
            const int rb = b0 + (mt + 1) * 16 + lr;
#pragma unroll
            for (int ks = 0; ks < 4; ++ks)
                an[ks] = *(const bf16x8*)(P + (size_t)rb * 128 + ks * 32 + quad * 8);
            cn2 = *(const f32x4*)(c + (size_t)rb * H_ + j4);
            hn  = *(const f32x4*)(h + (size_t)rb * H_ + j4);
            if (jx) xn = *(const f32x4*)(x + (size_t)rb * I_ + j4);
        }

        // MFMA: D[j][b] = Vc_tile . P_tile^T  (operands from registers)
        f32x4 acc[4] = {};
#pragma unroll
        for (int ks = 0; ks < 4; ++ks)
#pragma unroll
            for (int g = 0; g < 4; ++g)
                acc[g] = __builtin_amdgcn_mfma_f32_16x16x32_bf16(vfr[g][ks], a[ks], acc[g], 0, 0, 0);

        // epilogue: lane owns batch row (b0+mt*16+lr), j = j4..j4+3
        {
            const int brow = b0 + mt * 16 + lr;
            float hw[4], cw[4];
#pragma unroll
            for (int r = 0; r < 4; ++r) {
                const float xe = xv[r], he = hv[r];
                const float z  = dx[r] * xe + dh[r] * he;

                const float g0 = acc[0][r] - xe * cx[0][r] - he * ch[0][r] + bs[0][r] + z;
                const float g1 = acc[1][r] - xe * cx[1][r] - he * ch[1][r] + bs[1][r] + z;
                const float g2 = acc[2][r] - xe * cx[2][r] - he * ch[2][r] + bs[2][r] + z;
                const float g3 = acc[3][r] - xe * cx[3][r] - he * ch[3][r] + bs[3][r] + z;

                const float ig = sigmoidf_(g0);
                const float fg = sigmoidf_(g1);
                const float og = sigmoidf_(g2);
                const float ng = tanhf_(g3);

                cw[r] = fg * cv[r] + ig * ng;
                hw[r] = og * tanhf_(cw[r]);
            }
            f32x4 hq = { hw[0], hw[1], hw[2], hw[3] };
            f32x4 cq = { cw[0], cw[1], cw[2], cw[3] };
            __builtin_nontemporal_store(hq, (f32x4*)(out + (size_t)brow * H_ + j4));
            __builtin_nontemporal_store(cq, (f32x4*)(out + (size_t)B_ * H_ + (size_t)brow * H_ + j4));
        }

        if (mt < 3) {
#pragma unroll
            for (int ks = 0; ks < 4; ++ks) a[ks] = an[ks];
            xv = xn; hv = hn; cv = cn2;
        }
    }
}

// ---------------------------------------------------------------------------
extern "C" void kernel_launch(void* const* d_in, const int* in_sizes, int n_in,
                              void* d_out, int out_size, void* d_ws, size_t ws_size,
                              hipStream_t stream) {
    const float* x     = (const float*)d_in[0];
    const float* h     = (const float*)d_in[1];
    const float* c     = (const float*)d_in[2];
    const float* u_x   = (const float*)d_in[3];
    const float* u_h   = (const float*)d_in[4];
    const float* v_x   = (const float*)d_in[5];
    const float* v_h   = (const float*)d_in[6];
    const float* b_x   = (const float*)d_in[7];
    const float* b_h   = (const float*)d_in[8];
    const float* dia_x = (const float*)d_in[9];
    const float* dia_h = (const float*)d_in[10];
    float* out = (float*)d_out;

    char* ws = (char*)d_ws;
    short* P      = (short*)(ws);                                    // 2,097,152 B
    short* uxT    = (short*)(ws + 2097152);                          //    65,536
    short* uhT    = (short*)(ws + 2097152 + 65536);                  //   131,072
    short* Vc     = (short*)(ws + 2097152 + 65536 + 131072);         // 1,048,576
    float* coef_x = (float*)(ws + 2097152 + 65536 + 131072 + 1048576);
    float* coef_h = (float*)(ws + 2097152 + 65536 + 131072 + 1048576 + 8192);

    prep_kernel<<<2816, 256, 0, stream>>>(u_x, u_h, v_x, v_h, uxT, uhT, Vc, coef_x, coef_h);
    stage1_kernel<<<dim3(512, 2), 256, 0, stream>>>(x, h, uxT, uhT, P);
    stage2_kernel<<<dim3(128, 16), 256, 0, stream>>>(P, Vc, x, h, c,
                                                     coef_x, coef_h, b_x, b_h,
                                                     dia_x, dia_h, out);
}